// Round 1
// 1798.315 us; speedup vs baseline: 1.1812x; 1.1812x over previous
//
#include <hip/hip_runtime.h>

#define B_ 32
#define S_ 512
#define D_ 1024
#define H_ 16
#define DK_ 64
#define DFF_ 2048
#define L_ 4

typedef __attribute__((ext_vector_type(8))) short short8;
typedef __attribute__((ext_vector_type(4))) float f32x4;
typedef unsigned short u16;
typedef unsigned int u32;
typedef __attribute__((ext_vector_type(4))) u16 u16x4;
typedef __attribute__((ext_vector_type(8))) u16 u16x8;

__device__ __forceinline__ u16 f2bf(float f) {          // round-nearest-even
    u32 u = __float_as_uint(f);
    u = u + 0x7fffu + ((u >> 16) & 1u);
    return (u16)(u >> 16);
}
__device__ __forceinline__ u16 f2bf_t(float f) {        // truncate (cheap, for P)
    return (u16)(__float_as_uint(f) >> 16);
}
__device__ __forceinline__ float bf2f(u16 v) {
    return __uint_as_float(((u32)v) << 16);
}

__device__ __forceinline__ void async16(const u16* g, u16* l) {
    __builtin_amdgcn_global_load_lds((const __attribute__((address_space(1))) u32*)g,
                                     (__attribute__((address_space(3))) u32*)l, 16, 0, 0);
}

// ---------------------------------------------------------------------------
// GEMM: C[M,N] = A[M,K](bf16) @ Bt[N,K]^T(bf16) + bias[N].
// OUTM: 0 = fp32 row-major, 1 = bf16 row-major, 2 = bf16 V^T [b,h,d,s] layout.
//
// 256x256 tile, BK=64, 8 waves (2M x 4N), per-wave 128x64 output.
// 8-phase-style schedule (guide §5 template, re-derived race-free):
//   - LDS 128 KiB: A[2][256][64] + B[2][256][64] bf16, XOR-swizzled rows
//     (chunk ^= row&7 on 128 B rows -> 2-way bank aliasing = free).
//   - 4 phases per K-tile; phase p: {stage-issue | ds_read | barrier |
//     lgkmcnt(0) | setprio(1) | 16 MFMA | setprio(0) | barrier}.
//   - A-quarter of tile t+2 staged one phase behind its reader (rows die
//     phase-by-phase); B of tile t+2 staged while buf c^1 is being read
//     (B is consumed entirely in phase 0, held in registers).
//   - counted s_waitcnt vmcnt(7) at iter boundary: never drains to 0,
//     tile t+1 fully landed, 7 loads (tile t+2) stay in flight.
//   - bijective XCD swizzle: each XCD owns a contiguous band of M-panels.
// ---------------------------------------------------------------------------
#define READ_A(P)                                                              \
    afr[0][0] = *(const short8*)&lds[cb + arow + (2*(P)+0)*1024 + chv0];       \
    afr[0][1] = *(const short8*)&lds[cb + arow + (2*(P)+0)*1024 + chv1];       \
    afr[1][0] = *(const short8*)&lds[cb + arow + (2*(P)+1)*1024 + chv0];       \
    afr[1][1] = *(const short8*)&lds[cb + arow + (2*(P)+1)*1024 + chv1];

#define MFMA_PHASE(P)                                                          \
    __builtin_amdgcn_s_barrier();                                              \
    asm volatile("s_waitcnt lgkmcnt(0)" ::: "memory");                         \
    __builtin_amdgcn_sched_barrier(0);                                         \
    __builtin_amdgcn_s_setprio(1);                                             \
    _Pragma("unroll")                                                          \
    for (int mi2 = 0; mi2 < 2; mi2++) {                                        \
        _Pragma("unroll")                                                      \
        for (int ni = 0; ni < 4; ni++) {                                       \
            acc[2*(P)+mi2][ni] = __builtin_amdgcn_mfma_f32_16x16x32_bf16(      \
                afr[mi2][0], bfr[ni][0], acc[2*(P)+mi2][ni], 0, 0, 0);         \
            acc[2*(P)+mi2][ni] = __builtin_amdgcn_mfma_f32_16x16x32_bf16(      \
                afr[mi2][1], bfr[ni][1], acc[2*(P)+mi2][ni], 0, 0, 0);         \
        }                                                                      \
    }                                                                          \
    __builtin_amdgcn_s_setprio(0);

template<int RELU, int OUTM>
__global__ __launch_bounds__(512, 2)
void gemm256(const u16* __restrict__ A, const u16* __restrict__ Bt,
             const float* __restrict__ bias, void* __restrict__ C,
             int M, int N, int K)
{
    // [A buf0 | A buf1 | B buf0 | B buf1], each 256x64 bf16 = 16K u16
    __shared__ __align__(16) u16 lds[65536];
    const int t = threadIdx.x;
    const int w = t >> 6, l = t & 63;
    const int lane16 = l & 15, quad = l >> 4;
    const int wm = w >> 2, wn = w & 3;          // wave grid: 2 (M) x 4 (N)

    // bijective XCD swizzle (m204): XCD k owns a contiguous run of block ids;
    // within the run, bx (N) fastest -> A-panel reuse inside the XCD's L2.
    const int gx = gridDim.x;
    const int nwg = gx * gridDim.y;
    const int orig = blockIdx.y * gx + blockIdx.x;
    const int q8 = nwg >> 3, r8 = nwg & 7;
    const int xcd = orig & 7, sidx = orig >> 3;
    const int nid = (xcd < r8 ? xcd * (q8 + 1) : r8 * (q8 + 1) + (xcd - r8) * q8) + sidx;
    const int m0 = (nid / gx) * 256;
    const int n0 = (nid % gx) * 256;

    f32x4 acc[8][4];
#pragma unroll
    for (int i = 0; i < 8; i++)
#pragma unroll
        for (int j = 0; j < 4; j++) acc[i][j] = f32x4{0.f, 0.f, 0.f, 0.f};

    // ---- staging setup (rule #21: linear LDS dest, inverse-swizzled source)
    const int lr = l >> 3;                       // lane row within 8-row chunk
    const int xorcol = ((l & 7) ^ lr) * 8;       // logical k-offset (u16) of lane's chunk
    const int aw8 = (w < 4 ? w * 8 : 128 + (w - 4) * 8);
    const u16* Asrc = A + (size_t)(m0 + aw8 + lr) * K + xorcol;
    const u16* Bsrc = Bt + (size_t)(n0 + w * 8 + lr) * K + xorcol;

    auto stageA = [&](int tile, int q) {
        const int c = tile & 1;
        async16(Asrc + (size_t)(q * 32) * K + (tile << 6),
                &lds[c * 16384 + (aw8 + q * 32) * 64]);
    };
    auto stageB = [&](int tile, int j) {
        const int c = tile & 1;
        async16(Bsrc + (size_t)(j * 64) * K + (tile << 6),
                &lds[32768 + c * 16384 + (j * 64 + w * 8) * 64]);
    };

    // ---- ds_read fragment addressing (swizzled): chunk ^= row&7
    const int chv0 = ((0 + quad) ^ (lane16 & 7)) * 8;    // kf = 0
    const int chv1 = ((4 + quad) ^ (lane16 & 7)) * 8;    // kf = 1
    const int arow = (wm * 128 + lane16) * 64;           // + mi*1024 + chv
    const int brow = 32768 + (wn * 64 + lane16) * 64;    // + ni*1024 + chv

    const int NT = K >> 6;

    // ---- prologue: virtual iters -2/-1 of the steady-state staging stream
    stageA(0, 0); stageB(0, 0); stageB(0, 1);
    stageA(0, 1); stageB(0, 2); stageB(0, 3);
    stageA(0, 2);
    stageA(0, 3);
    stageA(1, 0); stageB(1, 0); stageB(1, 1);
    stageA(1, 1); stageB(1, 2); stageB(1, 3);
    stageA(1, 2);
    asm volatile("s_waitcnt vmcnt(7)" ::: "memory");   // tile 0 fully landed
    __builtin_amdgcn_sched_barrier(0);
    __builtin_amdgcn_s_barrier();

    for (int tt = 0; tt < NT; tt++) {
        const int cb = (tt & 1) * 16384;
        short8 bfr[4][2], afr[2][2];
        // ---- phase 0: B frags (whole tile, held in regs) + A mi 0,1
        if (tt + 1 < NT) stageA(tt + 1, 3);
#pragma unroll
        for (int ni = 0; ni < 4; ni++) {
            bfr[ni][0] = *(const short8*)&lds[cb + brow + ni * 1024 + chv0];
            bfr[ni][1] = *(const short8*)&lds[cb + brow + ni * 1024 + chv1];
        }
        READ_A(0)
        MFMA_PHASE(0)
        __builtin_amdgcn_s_barrier();
        // ---- phase 1
        if (tt + 2 < NT) { stageA(tt + 2, 0); stageB(tt + 2, 0); stageB(tt + 2, 1); }
        READ_A(1)
        MFMA_PHASE(1)
        __builtin_amdgcn_s_barrier();
        // ---- phase 2
        if (tt + 2 < NT) { stageA(tt + 2, 1); stageB(tt + 2, 2); stageB(tt + 2, 3); }
        READ_A(2)
        MFMA_PHASE(2)
        __builtin_amdgcn_s_barrier();
        // ---- phase 3
        if (tt + 2 < NT) stageA(tt + 2, 2);
        READ_A(3)
        MFMA_PHASE(3)
        if (tt + 2 < NT) asm volatile("s_waitcnt vmcnt(7)" ::: "memory");
        else             asm volatile("s_waitcnt vmcnt(0)" ::: "memory");
        __builtin_amdgcn_sched_barrier(0);
        __builtin_amdgcn_s_barrier();
    }

    // ---- epilogue
#pragma unroll
    for (int mi = 0; mi < 8; mi++) {
#pragma unroll
        for (int ni = 0; ni < 4; ni++) {
            int col = n0 + wn * 64 + ni * 16 + lane16;
            float bv = bias[col];
            if (OUTM == 2) {
                int tok0 = m0 + wm * 128 + mi * 16 + quad * 4;
                int bb = tok0 >> 9, s0 = tok0 & 511;
                int hh = col >> 6, dd = col & 63;
                u16x4 pk;
#pragma unroll
                for (int r2 = 0; r2 < 4; r2++) pk[r2] = f2bf(acc[mi][ni][r2] + bv);
                *(u16x4*)&((u16*)C)[(((size_t)bb * H_ + hh) * DK_ + dd) * S_ + s0] = pk;
            } else {
                int row = m0 + wm * 128 + mi * 16 + quad * 4;
#pragma unroll
                for (int r2 = 0; r2 < 4; r2++) {
                    float v = acc[mi][ni][r2] + bv;
                    if (RELU) v = fmaxf(v, 0.f);
                    size_t idx = (size_t)(row + r2) * N + col;
                    if (OUTM == 1) ((u16*)C)[idx] = f2bf(v);
                    else           ((float*)C)[idx] = v;
                }
            }
        }
    }
}

// ---------------------------------------------------------------------------
// Barrier-free transposed flash attention, max-free softmax.
// S^T = mfma(A=K, B=Q): per-lane i=lane16 -> row reductions mostly in-lane,
// P register quads are 4 consecutive j -> ds_write_b64 pack.
// O^T = mfma(A=V^T, B=P): 1/l is a per-lane scalar, no cross-lane bcast.
// No running max (scores bounded: |s*SC| << 127, exp2 cannot overflow).
// One wave = one 32-row band; bands {2p,2p+1,15-2p,14-2p} -> 18 tiles/block.
// qk: [b,s,h*64+d] (Q==K). vt: [b,h,d,s]. ao: [b,s,h*64+d].
// ---------------------------------------------------------------------------
__global__ __launch_bounds__(256, 3)
void attn_kernel(const u16* __restrict__ qk, const u16* __restrict__ vt,
                 u16* __restrict__ ao)
{
    __shared__ __align__(16) u16 sP[4][32 * 72];
    const int t = threadIdx.x, w = t >> 6, l = t & 63;
    const int lane16 = l & 15, quad = l >> 4;
    const int p = blockIdx.x;
    const int bh = blockIdx.y;
    const int b = bh >> 4, h = bh & 15;
    const int band = (w < 2) ? (2 * p + w) : (15 - 2 * p - (w - 2));
    const int band0 = band * 32;
    const u16* kb = qk + (size_t)b * S_ * D_ + h * DK_;
    const u16* vb = vt + (size_t)bh * DK_ * S_;
    u16* aob = ao + (size_t)b * S_ * D_ + h * DK_;
    const float SC = 0.125f * 1.44269504f;  // (1/sqrt(DK)) * log2(e)
    u16* myP = sP[w];

    // Q as B-operand fragments (same memory pattern as A-operand)
    short8 bq[2][2];
#pragma unroll
    for (int ii = 0; ii < 2; ii++)
#pragma unroll
        for (int kf = 0; kf < 2; kf++)
            bq[ii][kf] = *(const short8*)(kb + (size_t)(band0 + ii * 16 + lane16) * D_ +
                                          kf * 32 + quad * 8);

    f32x4 aco[4][2];                 // O^T accum: [d-tile][i-tile]
    float lsum[2] = {0.f, 0.f};      // per-lane partial softmax denominator
#pragma unroll
    for (int di = 0; di < 4; di++)
#pragma unroll
        for (int ii = 0; ii < 2; ii++) aco[di][ii] = f32x4{0.f, 0.f, 0.f, 0.f};

    const int ntiles = (band >> 1) + 1;
    for (int jt = 0; jt < ntiles; jt++) {
        const int j0 = jt * 64;
        const bool diag = (jt == ntiles - 1);

        // K as A-operand: aK[kf][ji]
        short8 aK[2][4];
#pragma unroll
        for (int kf = 0; kf < 2; kf++)
#pragma unroll
            for (int ji = 0; ji < 4; ji++)
                aK[kf][ji] = *(const short8*)(kb + (size_t)(j0 + ji * 16 + lane16) * D_ +
                                              kf * 32 + quad * 8);
        f32x4 sacc[4][2];
#pragma unroll
        for (int ji = 0; ji < 4; ji++)
#pragma unroll
            for (int ii = 0; ii < 2; ii++) sacc[ji][ii] = f32x4{0.f, 0.f, 0.f, 0.f};
#pragma unroll
        for (int kf = 0; kf < 2; kf++)
#pragma unroll
            for (int ji = 0; ji < 4; ji++)
#pragma unroll
                for (int ii = 0; ii < 2; ii++)
                    sacc[ji][ii] = __builtin_amdgcn_mfma_f32_16x16x32_bf16(
                        aK[kf][ji], bq[ii][kf], sacc[ji][ii], 0, 0, 0);

        // issue V^T A-fragments now so vmcnt overlaps the softmax VALU
        short8 aV[2][4];
#pragma unroll
        for (int kf = 0; kf < 2; kf++)
#pragma unroll
            for (int di = 0; di < 4; di++)
                aV[kf][di] = *(const short8*)(vb + (size_t)(di * 16 + lane16) * S_ +
                                              j0 + kf * 32 + quad * 8);

        // max-free softmax: p = exp2(s*SC); lsum accumulates per-lane
#pragma unroll
        for (int ii = 0; ii < 2; ii++) {
#pragma unroll
            for (int ji = 0; ji < 4; ji++) {
                u16x4 pk;
#pragma unroll
                for (int r2 = 0; r2 < 4; r2++) {
                    float v = sacc[ji][ii][r2] * SC;
                    if (diag) {
                        int j = j0 + ji * 16 + quad * 4 + r2;
                        int i = band0 + ii * 16 + lane16;
                        if (j >= i) v = -3e38f;   // strict causal
                    }
                    float pv = exp2f(v);          // masked -> 0
                    lsum[ii] += pv;
                    pk[r2] = f2bf_t(pv);
                }
                // P[i][j], 4 consecutive j per write
                *(u16x4*)&myP[(ii * 16 + lane16) * 72 + ji * 16 + quad * 4] = pk;
            }
        }

        // P as B-operand from LDS (wave-private; lgkmcnt-only)
        short8 pf[2][2];
#pragma unroll
        for (int kf = 0; kf < 2; kf++)
#pragma unroll
            for (int ii = 0; ii < 2; ii++)
                pf[kf][ii] = *(const short8*)&myP[(ii * 16 + lane16) * 72 +
                                                  kf * 32 + quad * 8];
#pragma unroll
        for (int kf = 0; kf < 2; kf++)
#pragma unroll
            for (int di = 0; di < 4; di++)
#pragma unroll
                for (int ii = 0; ii < 2; ii++)
                    aco[di][ii] = __builtin_amdgcn_mfma_f32_16x16x32_bf16(
                        aV[kf][di], pf[kf][ii], aco[di][ii], 0, 0, 0);
    }

    // fold partial denominators across the 4 quads (values replicated per i)
#pragma unroll
    for (int ii = 0; ii < 2; ii++) {
        lsum[ii] += __shfl_xor(lsum[ii], 16);
        lsum[ii] += __shfl_xor(lsum[ii], 32);
    }

    // write O (O^T layout: i=lane16, d=quad*4+r2); row 0 zeroed (zero_pad)
#pragma unroll
    for (int ii = 0; ii < 2; ii++) {
        int row = band0 + ii * 16 + lane16;
        float lv = lsum[ii];
        float inv = (row == 0 || !(lv > 0.f)) ? 0.f : 1.f / lv;
#pragma unroll
        for (int di = 0; di < 4; di++) {
            u16x4 o;
#pragma unroll
            for (int r2 = 0; r2 < 4; r2++) o[r2] = f2bf(aco[di][ii][r2] * inv);
            *(u16x4*)&aob[(size_t)row * D_ + di * 16 + quad * 4] = o;
        }
    }
}

// ---------------------------------------------------------------------------
// Fused residual + LayerNorm. xin: bf16 (XBF=1) or fp32. Writes bf16 master;
// optionally also fp32 (final output). f32_out may alias addv (per-thread RAW safe).
// ---------------------------------------------------------------------------
template<int XBF, int WF32>
__global__ __launch_bounds__(256)
void ln_kernel(const void* __restrict__ xin, const float* __restrict__ addv,
               const float* __restrict__ sc, const float* __restrict__ bi,
               u16* __restrict__ xb_out, float* __restrict__ f32_out)
{
    const int row = blockIdx.x;
    const int t = threadIdx.x;
    const int w = t >> 6, l = t & 63;
    __shared__ float red[8];
    f32x4 a;
    if (XBF) {
        u16x4 raw = ((const u16x4*)xin)[(size_t)row * 256 + t];
#pragma unroll
        for (int j = 0; j < 4; j++) a[j] = bf2f(raw[j]);
    } else {
        a = ((const f32x4*)xin)[(size_t)row * 256 + t];
    }
    f32x4 c = ((const f32x4*)(addv + (size_t)row * D_))[t];
    f32x4 v;
    float s1 = 0.f, s2 = 0.f;
#pragma unroll
    for (int j = 0; j < 4; j++) {
        v[j] = a[j] + c[j];
        s1 += v[j];
        s2 += v[j] * v[j];
    }
#pragma unroll
    for (int off = 32; off > 0; off >>= 1) {
        s1 += __shfl_xor(s1, off);
        s2 += __shfl_xor(s2, off);
    }
    if (l == 0) { red[w * 2] = s1; red[w * 2 + 1] = s2; }
    __syncthreads();
    s1 = red[0] + red[2] + red[4] + red[6];
    s2 = red[1] + red[3] + red[5] + red[7];
    float mean = s1 * (1.f / D_);
    float var = s2 * (1.f / D_) - mean * mean;
    float rstd = rsqrtf(var + 1e-5f);
    f32x4 s4 = ((const f32x4*)sc)[t];
    f32x4 b4 = ((const f32x4*)bi)[t];
    f32x4 o;
    u16x4 ob;
#pragma unroll
    for (int j = 0; j < 4; j++) {
        o[j] = (v[j] - mean) * rstd * s4[j] + b4[j];
        ob[j] = f2bf(o[j]);
    }
    ((u16x4*)(xb_out + (size_t)row * D_))[t] = ob;
    if (WF32) ((f32x4*)(f32_out + (size_t)row * D_))[t] = o;
}

// fp32 -> bf16 convert
__global__ void cvt_kernel(const float* __restrict__ in, u16* __restrict__ out, int n4)
{
    int i = blockIdx.x * blockDim.x + threadIdx.x;
    if (i < n4) {
        f32x4 v = ((const f32x4*)in)[i];
        u16x4 o;
#pragma unroll
        for (int j = 0; j < 4; j++) o[j] = f2bf(v[j]);
        ((u16x4*)out)[i] = o;
    }
}

// W[K,N] fp32 -> WT[N,K] bf16, 64x64 tiles
__device__ __forceinline__ void tconv_body(const float* W, u16* WT, int K, int N,
                                           int bx, int by, int t)
{
    __shared__ float tile[64][65];
    const int n0 = bx * 64, k0 = by * 64;
#pragma unroll
    for (int i = 0; i < 4; i++) {
        int kr = (t >> 4) + i * 16;
        int nc = (t & 15) * 4;
        f32x4 v = *(const f32x4*)&W[(size_t)(k0 + kr) * N + n0 + nc];
        tile[kr][nc] = v[0]; tile[kr][nc + 1] = v[1];
        tile[kr][nc + 2] = v[2]; tile[kr][nc + 3] = v[3];
    }
    __syncthreads();
#pragma unroll
    for (int i = 0; i < 4; i++) {
        int nr = (t >> 4) + i * 16;
        int kc = (t & 15) * 4;
        u16x4 o;
#pragma unroll
        for (int j = 0; j < 4; j++) o[j] = f2bf(tile[kc + j][nr]);
        *(u16x4*)&WT[(size_t)(n0 + nr) * K + k0 + kc] = o;
    }
}

// all 5 per-layer weights in one dispatch: 3*256 + 512 + 512 = 1792 tiles
__global__ __launch_bounds__(256)
void wconv_kernel(const float* __restrict__ Wk, const float* __restrict__ Wv,
                  const float* __restrict__ Wo, const float* __restrict__ W1f,
                  const float* __restrict__ W2f,
                  u16* __restrict__ wk, u16* __restrict__ wv, u16* __restrict__ wo,
                  u16* __restrict__ w1, u16* __restrict__ w2)
{
    const int idx = blockIdx.x;
    const float* W; u16* T; int K, N, bx, by;
    if (idx < 768) {
        int wsel = idx >> 8, t16 = idx & 255;
        W = (wsel == 0) ? Wk : (wsel == 1) ? Wv : Wo;
        T = (wsel == 0) ? wk : (wsel == 1) ? wv : wo;
        K = 1024; N = 1024; bx = t16 & 15; by = t16 >> 4;
    } else if (idx < 1280) {
        int i = idx - 768;
        W = W1f; T = w1; K = 1024; N = 2048; bx = i & 31; by = i >> 5;
    } else {
        int i = idx - 1280;
        W = W2f; T = w2; K = 2048; N = 1024; bx = i & 15; by = i >> 4;
    }
    tconv_body(W, T, K, N, bx, by, threadIdx.x);
}

extern "C" void kernel_launch(void* const* d_in, const int* in_sizes, int n_in,
                              void* d_out, int out_size, void* d_ws, size_t ws_size,
                              hipStream_t stream)
{
    const float* q_embed = (const float*)d_in[0];
    const float* qa_embed = (const float*)d_in[1];
    const float* Wk = (const float*)d_in[2];
    const float* bk = (const float*)d_in[3];
    const float* Wv = (const float*)d_in[4];
    const float* bv = (const float*)d_in[5];
    const float* Wo = (const float*)d_in[6];
    const float* bo = (const float*)d_in[7];
    const float* ln1_s = (const float*)d_in[8];
    const float* ln1_b = (const float*)d_in[9];
    const float* W1 = (const float*)d_in[10];
    const float* b1 = (const float*)d_in[11];
    const float* W2 = (const float*)d_in[12];
    const float* b2 = (const float*)d_in[13];
    const float* ln2_s = (const float*)d_in[14];
    const float* ln2_b = (const float*)d_in[15];
    (void)in_sizes; (void)n_in; (void)out_size;

    char* ws = (char*)d_ws;
    size_t off = 0;
    auto carve = [&](size_t bytes) -> char* {
        char* p = ws + off;
        off += (bytes + 255) & ~(size_t)255;
        return p;
    };
    const size_t NTOK = (size_t)B_ * S_;  // 16384
    u16* wk = (u16*)carve((size_t)D_ * D_ * 2);
    u16* wv = (u16*)carve((size_t)D_ * D_ * 2);
    u16* wo = (u16*)carve((size_t)D_ * D_ * 2);
    u16* w1 = (u16*)carve((size_t)D_ * DFF_ * 2);
    u16* w2 = (u16*)carve((size_t)DFF_ * D_ * 2);
    u16* x = (u16*)carve(NTOK * D_ * 2);           // bf16 residual master
    u16* U12 = (u16*)carve(NTOK * DFF_ * 2);       // [qkb | vbf] then hb
    u16* U3 = (u16*)carve(NTOK * D_ * 2);          // aob (and ybf in overlay mode)
    // try a separate ybf so qa_embed converts once; fall back to overlay if ws small
    size_t off_overlay = off;
    u16* ybf_sep = (u16*)carve(NTOK * D_ * 2);
    bool sep = (ws_size >= off);
    if (!sep) off = off_overlay;
    if (ws_size < off) return;

    u16* qkb = U12;
    u16* vbf = U12 + NTOK * D_;   // V^T [b,h,d,s]
    u16* hb = U12;
    u16* aob = U3;
    u16* ybf = sep ? ybf_sep : U3;
    float* of32 = (float*)d_out;  // fp32 scratch: attn-o / ffn2 outputs

    cvt_kernel<<<16384, 256, 0, stream>>>(q_embed, x, (int)(NTOK * D_ / 4));
    if (sep)
        cvt_kernel<<<16384, 256, 0, stream>>>(qa_embed, ybf, (int)(NTOK * D_ / 4));

    const dim3 G1024(4, 64), G2048(8, 64);   // 256x256 output tiles
    for (int lyr = 0; lyr < L_; lyr++) {
        const size_t wsq = (size_t)lyr * D_ * D_;
        const size_t wf1 = (size_t)lyr * D_ * DFF_;
        wconv_kernel<<<1792, 256, 0, stream>>>(Wk + wsq, Wv + wsq, Wo + wsq,
                                               W1 + wf1, W2 + wf1,
                                               wk, wv, wo, w1, w2);
        if (!sep)
            cvt_kernel<<<16384, 256, 0, stream>>>(qa_embed, ybf, (int)(NTOK * D_ / 4));
        // qk = x @ Wk + bk (bf16, row-major; serves as Q and K)
        gemm256<0, 1><<<G1024, 512, 0, stream>>>(x, wk, bk + lyr * D_,
                                                 qkb, (int)NTOK, D_, D_);
        // v = y @ Wv + bv, written directly as V^T [b,h,d,s]
        gemm256<0, 2><<<G1024, 512, 0, stream>>>(ybf, wv, bv + lyr * D_,
                                                 vbf, (int)NTOK, D_, D_);
        // barrier-free transposed causal attention
        attn_kernel<<<dim3(4, B_ * H_), 256, 0, stream>>>(qkb, vbf, aob);
        // o = attn_out @ Wo + bo (fp32 into d_out scratch)
        gemm256<0, 0><<<G1024, 512, 0, stream>>>(aob, wo, bo + lyr * D_,
                                                 of32, (int)NTOK, D_, D_);
        // x = LN1(x + o)
        if (lyr == 0)
            ln_kernel<0, 0><<<(int)NTOK, 256, 0, stream>>>(q_embed, of32,
                ln1_s + lyr * D_, ln1_b + lyr * D_, x, nullptr);
        else
            ln_kernel<1, 0><<<(int)NTOK, 256, 0, stream>>>(x, of32,
                ln1_s + lyr * D_, ln1_b + lyr * D_, x, nullptr);
        // h = relu(x @ W1 + b1)
        gemm256<1, 1><<<G2048, 512, 0, stream>>>(x, w1, b1 + lyr * DFF_,
                                                 hb, (int)NTOK, DFF_, D_);
        // f = h @ W2 + b2 (fp32 into d_out scratch)
        gemm256<0, 0><<<G1024, 512, 0, stream>>>(hb, w2, b2 + lyr * D_,
                                                 of32, (int)NTOK, D_, DFF_);
        // x = LN2(x + f); final layer also writes fp32 d_out
        if (lyr == L_ - 1)
            ln_kernel<1, 1><<<(int)NTOK, 256, 0, stream>>>(x, of32,
                ln2_s + lyr * D_, ln2_b + lyr * D_, x, (float*)d_out);
        else
            ln_kernel<1, 0><<<(int)NTOK, 256, 0, stream>>>(x, of32,
                ln2_s + lyr * D_, ln2_b + lyr * D_, x, nullptr);
    }
}

// Round 2
// 1792.637 us; speedup vs baseline: 1.1850x; 1.0032x over previous
//
#include <hip/hip_runtime.h>

#define B_ 32
#define S_ 512
#define D_ 1024
#define H_ 16
#define DK_ 64
#define DFF_ 2048
#define L_ 4

typedef __attribute__((ext_vector_type(8))) short short8;
typedef __attribute__((ext_vector_type(4))) float f32x4;
typedef unsigned short u16;
typedef unsigned int u32;
typedef __attribute__((ext_vector_type(4))) u16 u16x4;
typedef __attribute__((ext_vector_type(8))) u16 u16x8;

__device__ __forceinline__ u16 f2bf(float f) {          // round-nearest-even
    u32 u = __float_as_uint(f);
    u = u + 0x7fffu + ((u >> 16) & 1u);
    return (u16)(u >> 16);
}
__device__ __forceinline__ u16 f2bf_t(float f) {        // truncate (cheap, for P)
    return (u16)(__float_as_uint(f) >> 16);
}
__device__ __forceinline__ float bf2f(u16 v) {
    return __uint_as_float(((u32)v) << 16);
}

__device__ __forceinline__ void async16(const u16* g, u16* l) {
    __builtin_amdgcn_global_load_lds((const __attribute__((address_space(1))) u32*)g,
                                     (__attribute__((address_space(3))) u32*)l, 16, 0, 0);
}

// ---------------------------------------------------------------------------
// GEMM: C[M,N] = A[M,K](bf16) @ Bt[N,K]^T(bf16) + bias[N].
// OUTM: 0 = fp32 row-major, 1 = bf16 row-major, 2 = bf16 V^T [b,h,d,s] layout.
//
// 256x256 tile, BK=64, 8 waves (2M x 4N), per-wave 128x64 output.
// Software-pipelined 8-phase schedule (ds_read drain hidden under MFMA):
//   - phases = (kf, mi-pair): ph 0-3 = kf0 x m0-3, ph 4-7 = kf1 x m0-3.
//     8 MFMA/phase; every acc element accumulated twice (kf0 then kf1).
//   - A frags ping-pong one phase ahead (a0/a1); B kf0 read at tile
//     boundary, B kf1 read during ph1/ph2 (drains under MFMA).
//   - counted lgkmcnt per phase retires only last phase's reads; this
//     phase's read drain overlaps this phase's MFMA cluster.
//   - ONE barrier per phase: reader counted-lgkm < reader MFMA < barrier
//     < any wave's next-phase stage issue (WAR-safe).
//   - counted vmcnt(6) at boundary (never 0 mid-loop); boundary reads of
//     next tile's B-kf0/A-m0 after the barrier (cross-wave visibility).
//   - bijective XCD swizzle: each XCD owns a contiguous band of M-panels.
// ---------------------------------------------------------------------------
#define RD_A2(dst, CBX, MP, CHV)                                               \
    dst[0] = *(const short8*)&lds[(CBX) + arow + (2*(MP)+0)*1024 + (CHV)];     \
    dst[1] = *(const short8*)&lds[(CBX) + arow + (2*(MP)+1)*1024 + (CHV)];

#define RD_B4(dst, CBX, CHV)                                                   \
    _Pragma("unroll")                                                          \
    for (int ni = 0; ni < 4; ni++)                                             \
        dst[ni] = *(const short8*)&lds[32768 + (CBX) + browr + ni*1024 + (CHV)];

#define MF8(MP, ASRC, BSRC, LGN)                                               \
    asm volatile("s_waitcnt lgkmcnt(" #LGN ")" ::: "memory");                  \
    __builtin_amdgcn_sched_barrier(0);                                         \
    __builtin_amdgcn_s_setprio(1);                                             \
    _Pragma("unroll")                                                          \
    for (int ni = 0; ni < 4; ni++) {                                           \
        acc[2*(MP)+0][ni] = __builtin_amdgcn_mfma_f32_16x16x32_bf16(           \
            ASRC[0], BSRC[ni], acc[2*(MP)+0][ni], 0, 0, 0);                    \
        acc[2*(MP)+1][ni] = __builtin_amdgcn_mfma_f32_16x16x32_bf16(           \
            ASRC[1], BSRC[ni], acc[2*(MP)+1][ni], 0, 0, 0);                    \
    }                                                                          \
    __builtin_amdgcn_s_setprio(0);                                             \
    __builtin_amdgcn_s_barrier();                                              \
    __builtin_amdgcn_sched_barrier(0);

template<int RELU, int OUTM>
__global__ __launch_bounds__(512, 2)
void gemm256(const u16* __restrict__ A, const u16* __restrict__ Bt,
             const float* __restrict__ bias, void* __restrict__ C,
             int M, int N, int K)
{
    // [A buf0 | A buf1 | B buf0 | B buf1], each 256x64 bf16 = 16K u16
    __shared__ __align__(16) u16 lds[65536];
    const int t = threadIdx.x;
    const int w = t >> 6, l = t & 63;
    const int lane16 = l & 15, quad = l >> 4;
    const int wm = w >> 2, wn = w & 3;          // wave grid: 2 (M) x 4 (N)

    // bijective XCD swizzle (m204)
    const int gx = gridDim.x;
    const int nwg = gx * gridDim.y;
    const int orig = blockIdx.y * gx + blockIdx.x;
    const int q8 = nwg >> 3, r8 = nwg & 7;
    const int xcd = orig & 7, sidx = orig >> 3;
    const int nid = (xcd < r8 ? xcd * (q8 + 1) : r8 * (q8 + 1) + (xcd - r8) * q8) + sidx;
    const int m0 = (nid / gx) * 256;
    const int n0 = (nid % gx) * 256;

    f32x4 acc[8][4];
#pragma unroll
    for (int i = 0; i < 8; i++)
#pragma unroll
        for (int j = 0; j < 4; j++) acc[i][j] = f32x4{0.f, 0.f, 0.f, 0.f};

    // ---- staging setup (rule #21: linear LDS dest, inverse-swizzled source)
    const int lr = l >> 3;                       // lane row within 8-row chunk
    const int xorcol = ((l & 7) ^ lr) * 8;       // logical k-offset (u16) of lane's chunk
    const int aw8 = (w < 4 ? w * 8 : 128 + (w - 4) * 8);
    const u16* Asrc = A + (size_t)(m0 + aw8 + lr) * K + xorcol;
    const u16* Bsrc = Bt + (size_t)(n0 + w * 8 + lr) * K + xorcol;

    auto stageA = [&](int tile, int q) {
        const int c = tile & 1;
        async16(Asrc + (size_t)(q * 32) * K + (tile << 6),
                &lds[c * 16384 + (aw8 + q * 32) * 64]);
    };
    auto stageB = [&](int tile, int j) {
        const int c = tile & 1;
        async16(Bsrc + (size_t)(j * 64) * K + (tile << 6),
                &lds[32768 + c * 16384 + (j * 64 + w * 8) * 64]);
    };

    // ---- ds_read fragment addressing (swizzled): chunk ^= row&7
    const int chv0 = ((0 + quad) ^ (lane16 & 7)) * 8;    // kf = 0
    const int chv1 = ((4 + quad) ^ (lane16 & 7)) * 8;    // kf = 1
    const int arow  = (wm * 128 + lane16) * 64;          // + mi*1024 + chv
    const int browr = (wn * 64 + lane16) * 64;           // + 32768 + cb + ni*1024 + chv

    const int NT = K >> 6;   // >= 2 always here (K in {1024, 2048})

    // ---- prologue: tile0 (8 loads, oldest), tile1 (A0..B2 = 6 loads)
    stageA(0, 0); stageB(0, 0); stageA(0, 1); stageB(0, 1);
    stageA(0, 2); stageB(0, 2); stageA(0, 3); stageB(0, 3);
    stageA(1, 0); stageB(1, 0); stageA(1, 1); stageB(1, 1);
    stageA(1, 2); stageB(1, 2);
    asm volatile("s_waitcnt vmcnt(6)" ::: "memory");   // tile 0 fully landed
    __builtin_amdgcn_sched_barrier(0);
    __builtin_amdgcn_s_barrier();

    short8 a0[2], a1[2], bk0[4], bk1[4];
    // boundary reads for tile 0: whole B-kf0 + A m-pair0 kf0
    RD_B4(bk0, 0, chv0)
    RD_A2(a0, 0, 0, chv0)

    for (int tt = 0; tt < NT; tt++) {
        const int cb  = (tt & 1) << 14;
        const int cbn = ((tt + 1) & 1) << 14;
        const bool hn1 = (tt + 1 < NT);
        const bool hn2 = (tt + 2 < NT);

        // ph0 (kf0,m0): use a0; prefetch a1 <- m1 kf0
        RD_A2(a1, cb, 1, chv0)
        MF8(0, a0, bk0, 2)
        // ph1 (kf0,m1): stage tile+1 tail (barrier-protected vs boundary reads)
        if (hn1) { stageA(tt + 1, 3); stageB(tt + 1, 3); }
        RD_A2(a0, cb, 2, chv0)
        bk1[0] = *(const short8*)&lds[32768 + cb + browr + 0 * 1024 + chv1];
        bk1[1] = *(const short8*)&lds[32768 + cb + browr + 1 * 1024 + chv1];
        MF8(1, a1, bk0, 4)
        // ph2 (kf0,m2)
        RD_A2(a1, cb, 3, chv0)
        bk1[2] = *(const short8*)&lds[32768 + cb + browr + 2 * 1024 + chv1];
        bk1[3] = *(const short8*)&lds[32768 + cb + browr + 3 * 1024 + chv1];
        MF8(2, a0, bk0, 6)
        // ph3 (kf0,m3): prefetch a0 <- m0 kf1
        RD_A2(a0, cb, 0, chv1)
        MF8(3, a1, bk0, 4)
        // ph4 (kf1,m0)
        RD_A2(a1, cb, 1, chv1)
        MF8(0, a0, bk1, 2)
        // ph5 (kf1,m1): stage tile+2 first quarter
        if (hn2) { stageA(tt + 2, 0); stageB(tt + 2, 0); }
        RD_A2(a0, cb, 2, chv1)
        MF8(1, a1, bk1, 2)
        // ph6 (kf1,m2)
        if (hn2) { stageA(tt + 2, 1); stageB(tt + 2, 1); }
        RD_A2(a1, cb, 3, chv1)
        MF8(2, a0, bk1, 2)
        // ph7 (kf1,m3): boundary — vmcnt, barrier, next-tile boundary reads
        if (hn2) { stageA(tt + 2, 2); stageB(tt + 2, 2); }
        if (hn2) asm volatile("s_waitcnt vmcnt(6)" ::: "memory");
        else     asm volatile("s_waitcnt vmcnt(0)" ::: "memory");
        __builtin_amdgcn_sched_barrier(0);
        __builtin_amdgcn_s_barrier();
        __builtin_amdgcn_sched_barrier(0);
        if (hn1) {
            RD_B4(bk0, cbn, chv0)
            RD_A2(a0, cbn, 0, chv0)
            MF8(3, a1, bk1, 6)
        } else {
            MF8(3, a1, bk1, 0)
        }
    }

    // ---- epilogue
#pragma unroll
    for (int mi = 0; mi < 8; mi++) {
#pragma unroll
        for (int ni = 0; ni < 4; ni++) {
            int col = n0 + wn * 64 + ni * 16 + lane16;
            float bv = bias[col];
            if (OUTM == 2) {
                int tok0 = m0 + wm * 128 + mi * 16 + quad * 4;
                int bb = tok0 >> 9, s0 = tok0 & 511;
                int hh = col >> 6, dd = col & 63;
                u16x4 pk;
#pragma unroll
                for (int r2 = 0; r2 < 4; r2++) pk[r2] = f2bf(acc[mi][ni][r2] + bv);
                *(u16x4*)&((u16*)C)[(((size_t)bb * H_ + hh) * DK_ + dd) * S_ + s0] = pk;
            } else {
                int row = m0 + wm * 128 + mi * 16 + quad * 4;
#pragma unroll
                for (int r2 = 0; r2 < 4; r2++) {
                    float v = acc[mi][ni][r2] + bv;
                    if (RELU) v = fmaxf(v, 0.f);
                    size_t idx = (size_t)(row + r2) * N + col;
                    if (OUTM == 1) ((u16*)C)[idx] = f2bf(v);
                    else           ((float*)C)[idx] = v;
                }
            }
        }
    }
}

// ---------------------------------------------------------------------------
// Barrier-free transposed flash attention, max-free softmax. (unchanged)
// ---------------------------------------------------------------------------
__global__ __launch_bounds__(256, 3)
void attn_kernel(const u16* __restrict__ qk, const u16* __restrict__ vt,
                 u16* __restrict__ ao)
{
    __shared__ __align__(16) u16 sP[4][32 * 72];
    const int t = threadIdx.x, w = t >> 6, l = t & 63;
    const int lane16 = l & 15, quad = l >> 4;
    const int p = blockIdx.x;
    const int bh = blockIdx.y;
    const int b = bh >> 4, h = bh & 15;
    const int band = (w < 2) ? (2 * p + w) : (15 - 2 * p - (w - 2));
    const int band0 = band * 32;
    const u16* kb = qk + (size_t)b * S_ * D_ + h * DK_;
    const u16* vb = vt + (size_t)bh * DK_ * S_;
    u16* aob = ao + (size_t)b * S_ * D_ + h * DK_;
    const float SC = 0.125f * 1.44269504f;  // (1/sqrt(DK)) * log2(e)
    u16* myP = sP[w];

    short8 bq[2][2];
#pragma unroll
    for (int ii = 0; ii < 2; ii++)
#pragma unroll
        for (int kf = 0; kf < 2; kf++)
            bq[ii][kf] = *(const short8*)(kb + (size_t)(band0 + ii * 16 + lane16) * D_ +
                                          kf * 32 + quad * 8);

    f32x4 aco[4][2];
    float lsum[2] = {0.f, 0.f};
#pragma unroll
    for (int di = 0; di < 4; di++)
#pragma unroll
        for (int ii = 0; ii < 2; ii++) aco[di][ii] = f32x4{0.f, 0.f, 0.f, 0.f};

    const int ntiles = (band >> 1) + 1;
    for (int jt = 0; jt < ntiles; jt++) {
        const int j0 = jt * 64;
        const bool diag = (jt == ntiles - 1);

        short8 aK[2][4];
#pragma unroll
        for (int kf = 0; kf < 2; kf++)
#pragma unroll
            for (int ji = 0; ji < 4; ji++)
                aK[kf][ji] = *(const short8*)(kb + (size_t)(j0 + ji * 16 + lane16) * D_ +
                                              kf * 32 + quad * 8);
        f32x4 sacc[4][2];
#pragma unroll
        for (int ji = 0; ji < 4; ji++)
#pragma unroll
            for (int ii = 0; ii < 2; ii++) sacc[ji][ii] = f32x4{0.f, 0.f, 0.f, 0.f};
#pragma unroll
        for (int kf = 0; kf < 2; kf++)
#pragma unroll
            for (int ji = 0; ji < 4; ji++)
#pragma unroll
                for (int ii = 0; ii < 2; ii++)
                    sacc[ji][ii] = __builtin_amdgcn_mfma_f32_16x16x32_bf16(
                        aK[kf][ji], bq[ii][kf], sacc[ji][ii], 0, 0, 0);

        short8 aV[2][4];
#pragma unroll
        for (int kf = 0; kf < 2; kf++)
#pragma unroll
            for (int di = 0; di < 4; di++)
                aV[kf][di] = *(const short8*)(vb + (size_t)(di * 16 + lane16) * S_ +
                                              j0 + kf * 32 + quad * 8);

#pragma unroll
        for (int ii = 0; ii < 2; ii++) {
#pragma unroll
            for (int ji = 0; ji < 4; ji++) {
                u16x4 pk;
#pragma unroll
                for (int r2 = 0; r2 < 4; r2++) {
                    float v = sacc[ji][ii][r2] * SC;
                    if (diag) {
                        int j = j0 + ji * 16 + quad * 4 + r2;
                        int i = band0 + ii * 16 + lane16;
                        if (j >= i) v = -3e38f;   // strict causal
                    }
                    float pv = exp2f(v);
                    lsum[ii] += pv;
                    pk[r2] = f2bf_t(pv);
                }
                *(u16x4*)&myP[(ii * 16 + lane16) * 72 + ji * 16 + quad * 4] = pk;
            }
        }

        short8 pf[2][2];
#pragma unroll
        for (int kf = 0; kf < 2; kf++)
#pragma unroll
            for (int ii = 0; ii < 2; ii++)
                pf[kf][ii] = *(const short8*)&myP[(ii * 16 + lane16) * 72 +
                                                  kf * 32 + quad * 8];
#pragma unroll
        for (int kf = 0; kf < 2; kf++)
#pragma unroll
            for (int di = 0; di < 4; di++)
#pragma unroll
                for (int ii = 0; ii < 2; ii++)
                    aco[di][ii] = __builtin_amdgcn_mfma_f32_16x16x32_bf16(
                        aV[kf][di], pf[kf][ii], aco[di][ii], 0, 0, 0);
    }

#pragma unroll
    for (int ii = 0; ii < 2; ii++) {
        lsum[ii] += __shfl_xor(lsum[ii], 16);
        lsum[ii] += __shfl_xor(lsum[ii], 32);
    }

#pragma unroll
    for (int ii = 0; ii < 2; ii++) {
        int row = band0 + ii * 16 + lane16;
        float lv = lsum[ii];
        float inv = (row == 0 || !(lv > 0.f)) ? 0.f : 1.f / lv;
#pragma unroll
        for (int di = 0; di < 4; di++) {
            u16x4 o;
#pragma unroll
            for (int r2 = 0; r2 < 4; r2++) o[r2] = f2bf(aco[di][ii][r2] * inv);
            *(u16x4*)&aob[(size_t)row * D_ + di * 16 + quad * 4] = o;
        }
    }
}

// ---------------------------------------------------------------------------
// Fused residual + LayerNorm. (unchanged)
// ---------------------------------------------------------------------------
template<int XBF, int WF32>
__global__ __launch_bounds__(256)
void ln_kernel(const void* __restrict__ xin, const float* __restrict__ addv,
               const float* __restrict__ sc, const float* __restrict__ bi,
               u16* __restrict__ xb_out, float* __restrict__ f32_out)
{
    const int row = blockIdx.x;
    const int t = threadIdx.x;
    const int w = t >> 6, l = t & 63;
    __shared__ float red[8];
    f32x4 a;
    if (XBF) {
        u16x4 raw = ((const u16x4*)xin)[(size_t)row * 256 + t];
#pragma unroll
        for (int j = 0; j < 4; j++) a[j] = bf2f(raw[j]);
    } else {
        a = ((const f32x4*)xin)[(size_t)row * 256 + t];
    }
    f32x4 c = ((const f32x4*)(addv + (size_t)row * D_))[t];
    f32x4 v;
    float s1 = 0.f, s2 = 0.f;
#pragma unroll
    for (int j = 0; j < 4; j++) {
        v[j] = a[j] + c[j];
        s1 += v[j];
        s2 += v[j] * v[j];
    }
#pragma unroll
    for (int off = 32; off > 0; off >>= 1) {
        s1 += __shfl_xor(s1, off);
        s2 += __shfl_xor(s2, off);
    }
    if (l == 0) { red[w * 2] = s1; red[w * 2 + 1] = s2; }
    __syncthreads();
    s1 = red[0] + red[2] + red[4] + red[6];
    s2 = red[1] + red[3] + red[5] + red[7];
    float mean = s1 * (1.f / D_);
    float var = s2 * (1.f / D_) - mean * mean;
    float rstd = rsqrtf(var + 1e-5f);
    f32x4 s4 = ((const f32x4*)sc)[t];
    f32x4 b4 = ((const f32x4*)bi)[t];
    f32x4 o;
    u16x4 ob;
#pragma unroll
    for (int j = 0; j < 4; j++) {
        o[j] = (v[j] - mean) * rstd * s4[j] + b4[j];
        ob[j] = f2bf(o[j]);
    }
    ((u16x4*)(xb_out + (size_t)row * D_))[t] = ob;
    if (WF32) ((f32x4*)(f32_out + (size_t)row * D_))[t] = o;
}

// fp32 -> bf16 convert
__global__ void cvt_kernel(const float* __restrict__ in, u16* __restrict__ out, int n4)
{
    int i = blockIdx.x * blockDim.x + threadIdx.x;
    if (i < n4) {
        f32x4 v = ((const f32x4*)in)[i];
        u16x4 o;
#pragma unroll
        for (int j = 0; j < 4; j++) o[j] = f2bf(v[j]);
        ((u16x4*)out)[i] = o;
    }
}

// W[K,N] fp32 -> WT[N,K] bf16, 64x64 tiles
__device__ __forceinline__ void tconv_body(const float* W, u16* WT, int K, int N,
                                           int bx, int by, int t)
{
    __shared__ float tile[64][65];
    const int n0 = bx * 64, k0 = by * 64;
#pragma unroll
    for (int i = 0; i < 4; i++) {
        int kr = (t >> 4) + i * 16;
        int nc = (t & 15) * 4;
        f32x4 v = *(const f32x4*)&W[(size_t)(k0 + kr) * N + n0 + nc];
        tile[kr][nc] = v[0]; tile[kr][nc + 1] = v[1];
        tile[kr][nc + 2] = v[2]; tile[kr][nc + 3] = v[3];
    }
    __syncthreads();
#pragma unroll
    for (int i = 0; i < 4; i++) {
        int nr = (t >> 4) + i * 16;
        int kc = (t & 15) * 4;
        u16x4 o;
#pragma unroll
        for (int j = 0; j < 4; j++) o[j] = f2bf(tile[kc + j][nr]);
        *(u16x4*)&WT[(size_t)(n0 + nr) * K + k0 + kc] = o;
    }
}

// all 5 per-layer weights in one dispatch: 3*256 + 512 + 512 = 1792 tiles
__global__ __launch_bounds__(256)
void wconv_kernel(const float* __restrict__ Wk, const float* __restrict__ Wv,
                  const float* __restrict__ Wo, const float* __restrict__ W1f,
                  const float* __restrict__ W2f,
                  u16* __restrict__ wk, u16* __restrict__ wv, u16* __restrict__ wo,
                  u16* __restrict__ w1, u16* __restrict__ w2)
{
    const int idx = blockIdx.x;
    const float* W; u16* T; int K, N, bx, by;
    if (idx < 768) {
        int wsel = idx >> 8, t16 = idx & 255;
        W = (wsel == 0) ? Wk : (wsel == 1) ? Wv : Wo;
        T = (wsel == 0) ? wk : (wsel == 1) ? wv : wo;
        K = 1024; N = 1024; bx = t16 & 15; by = t16 >> 4;
    } else if (idx < 1280) {
        int i = idx - 768;
        W = W1f; T = w1; K = 1024; N = 2048; bx = i & 31; by = i >> 5;
    } else {
        int i = idx - 1280;
        W = W2f; T = w2; K = 2048; N = 1024; bx = i & 15; by = i >> 4;
    }
    tconv_body(W, T, K, N, bx, by, threadIdx.x);
}

extern "C" void kernel_launch(void* const* d_in, const int* in_sizes, int n_in,
                              void* d_out, int out_size, void* d_ws, size_t ws_size,
                              hipStream_t stream)
{
    const float* q_embed = (const float*)d_in[0];
    const float* qa_embed = (const float*)d_in[1];
    const float* Wk = (const float*)d_in[2];
    const float* bk = (const float*)d_in[3];
    const float* Wv = (const float*)d_in[4];
    const float* bv = (const float*)d_in[5];
    const float* Wo = (const float*)d_in[6];
    const float* bo = (const float*)d_in[7];
    const float* ln1_s = (const float*)d_in[8];
    const float* ln1_b = (const float*)d_in[9];
    const float* W1 = (const float*)d_in[10];
    const float* b1 = (const float*)d_in[11];
    const float* W2 = (const float*)d_in[12];
    const float* b2 = (const float*)d_in[13];
    const float* ln2_s = (const float*)d_in[14];
    const float* ln2_b = (const float*)d_in[15];
    (void)in_sizes; (void)n_in; (void)out_size;

    char* ws = (char*)d_ws;
    size_t off = 0;
    auto carve = [&](size_t bytes) -> char* {
        char* p = ws + off;
        off += (bytes + 255) & ~(size_t)255;
        return p;
    };
    const size_t NTOK = (size_t)B_ * S_;  // 16384
    u16* wk = (u16*)carve((size_t)D_ * D_ * 2);
    u16* wv = (u16*)carve((size_t)D_ * D_ * 2);
    u16* wo = (u16*)carve((size_t)D_ * D_ * 2);
    u16* w1 = (u16*)carve((size_t)D_ * DFF_ * 2);
    u16* w2 = (u16*)carve((size_t)DFF_ * D_ * 2);
    u16* x = (u16*)carve(NTOK * D_ * 2);           // bf16 residual master
    u16* U12 = (u16*)carve(NTOK * DFF_ * 2);       // [qkb | vbf] then hb
    u16* U3 = (u16*)carve(NTOK * D_ * 2);          // aob (and ybf in overlay mode)
    size_t off_overlay = off;
    u16* ybf_sep = (u16*)carve(NTOK * D_ * 2);
    bool sep = (ws_size >= off);
    if (!sep) off = off_overlay;
    if (ws_size < off) return;

    u16* qkb = U12;
    u16* vbf = U12 + NTOK * D_;   // V^T [b,h,d,s]
    u16* hb = U12;
    u16* aob = U3;
    u16* ybf = sep ? ybf_sep : U3;
    float* of32 = (float*)d_out;  // fp32 scratch: attn-o / ffn2 outputs

    cvt_kernel<<<16384, 256, 0, stream>>>(q_embed, x, (int)(NTOK * D_ / 4));
    if (sep)
        cvt_kernel<<<16384, 256, 0, stream>>>(qa_embed, ybf, (int)(NTOK * D_ / 4));

    const dim3 G1024(4, 64), G2048(8, 64);   // 256x256 output tiles
    for (int lyr = 0; lyr < L_; lyr++) {
        const size_t wsq = (size_t)lyr * D_ * D_;
        const size_t wf1 = (size_t)lyr * D_ * DFF_;
        wconv_kernel<<<1792, 256, 0, stream>>>(Wk + wsq, Wv + wsq, Wo + wsq,
                                               W1 + wf1, W2 + wf1,
                                               wk, wv, wo, w1, w2);
        if (!sep)
            cvt_kernel<<<16384, 256, 0, stream>>>(qa_embed, ybf, (int)(NTOK * D_ / 4));
        // qk = x @ Wk + bk (bf16, row-major; serves as Q and K)
        gemm256<0, 1><<<G1024, 512, 0, stream>>>(x, wk, bk + lyr * D_,
                                                 qkb, (int)NTOK, D_, D_);
        // v = y @ Wv + bv, written directly as V^T [b,h,d,s]
        gemm256<0, 2><<<G1024, 512, 0, stream>>>(ybf, wv, bv + lyr * D_,
                                                 vbf, (int)NTOK, D_, D_);
        // barrier-free transposed causal attention
        attn_kernel<<<dim3(4, B_ * H_), 256, 0, stream>>>(qkb, vbf, aob);
        // o = attn_out @ Wo + bo (fp32 into d_out scratch)
        gemm256<0, 0><<<G1024, 512, 0, stream>>>(aob, wo, bo + lyr * D_,
                                                 of32, (int)NTOK, D_, D_);
        // x = LN1(x + o)
        if (lyr == 0)
            ln_kernel<0, 0><<<(int)NTOK, 256, 0, stream>>>(q_embed, of32,
                ln1_s + lyr * D_, ln1_b + lyr * D_, x, nullptr);
        else
            ln_kernel<1, 0><<<(int)NTOK, 256, 0, stream>>>(x, of32,
                ln1_s + lyr * D_, ln1_b + lyr * D_, x, nullptr);
        // h = relu(x @ W1 + b1)
        gemm256<1, 1><<<G2048, 512, 0, stream>>>(x, w1, b1 + lyr * DFF_,
                                                 hb, (int)NTOK, DFF_, D_);
        // f = h @ W2 + b2 (fp32 into d_out scratch)
        gemm256<0, 0><<<G1024, 512, 0, stream>>>(hb, w2, b2 + lyr * D_,
                                                 of32, (int)NTOK, D_, DFF_);
        // x = LN2(x + f); final layer also writes fp32 d_out
        if (lyr == L_ - 1)
            ln_kernel<1, 1><<<(int)NTOK, 256, 0, stream>>>(x, of32,
                ln2_s + lyr * D_, ln2_b + lyr * D_, x, (float*)d_out);
        else
            ln_kernel<1, 0><<<(int)NTOK, 256, 0, stream>>>(x, of32,
                ln2_s + lyr * D_, ln2_b + lyr * D_, x, nullptr);
    }
}